// Round 4
// baseline (234.919 us; speedup 1.0000x reference)
//
#include <hip/hip_runtime.h>
#include <math.h>

// Problem constants
#define D 64
#define K 512
#define NROWS 65536
#define DECAY 0.99f
#define ONE_MINUS_DECAY (1.0f - 0.99f)
#define COMMIT 0.25f

// ws layout (float offsets)
#define WS_DWT    0              // [K][D] = 32768 floats, dw accumulator (zeroed)
#define WS_CNT    32768          // [K] int histogram / rank counters (zeroed)
#define WS_LPART  33280          // [32] loss partial sums (zeroed)
#define WS_ZERO4  8336           // float4 count zeroed by prep (33344 floats)
#define WS_ESQ    33344          // [K]   ||e_k||^2
#define WS_ET     33856          // [K][D] fp32 embeddings transposed (gather)
#define WS_EF     66624          // f16 MFMA B-fragments: 8192 x 16B = 32768 floats
#define WS_PK     99392          // [N] int packed (rank<<9 | k)
#define WS_PERM   164928         // [N] int packed (row<<9 | k)

// out layout (float offsets) — unchanged
#define OUT_Q     0
#define OUT_LOSS  4194304
#define OUT_PERP  4194305
#define OUT_IDX   4194306
#define OUT_NEMB  4259842
#define OUT_HCS   4292610
#define OUT_HDW   4293122

typedef _Float16 f16x8 __attribute__((ext_vector_type(8)));
typedef float    f32x16 __attribute__((ext_vector_type(16)));

// ---------------- prep: zero accum + e_t + ||e||^2 + f16 hi/lo B-fragments ---
// B-fragment layout for v_mfma_f32_32x32x16_f16:
//   lane l supplies col = tile*32 + (l&31), k = (l>>5)*8 + j (j=0..7)
// fragment block index i = ((t*4 + s)*2 + h)*64 + l  (s=kstep, h=0 hi / 1 lo)
__global__ void vq_prep(const float* __restrict__ emb,  // [D][K]
                        float* __restrict__ ws)
{
    int i = blockIdx.x * 256 + threadIdx.x;   // 0..32767 (128 blocks)
    if (i < WS_ZERO4) {                       // zero dw_t + cnt + loss parts
        ((float4*)ws)[i] = make_float4(0.f, 0.f, 0.f, 0.f);
    }
    if (i < K * D) {                          // e_t[k][d] = emb[d][k]
        int k = i >> 6, d = i & 63;
        ws[WS_ET + i] = emb[d * K + k];
    }
    if (i < K) {                              // ||e_k||^2
        float s = 0.f;
        for (int d = 0; d < D; ++d) { float v = emb[d * K + i]; s += v * v; }
        ws[WS_ESQ + i] = s;
    }
    if (i < 8192) {                           // f16 hi/lo fragment buffer
        int l = i & 63, h = (i >> 6) & 1, s = (i >> 7) & 3, t = i >> 9;
        int col = t * 32 + (l & 31);
        int d0  = s * 16 + ((l >> 5) << 3);
        f16x8 frag;
#pragma unroll
        for (int j = 0; j < 8; ++j) {
            float v = emb[(d0 + j) * K + col];
            _Float16 hv = (_Float16)v;
            frag[j] = h ? (_Float16)(v - (float)hv) : hv;
        }
        ((f16x8*)(ws + WS_EF))[i] = frag;
    }
}

// ---------------- main: MFMA distances, K-split x4 across waves --------------
// Block = 4 waves = ONE 32-row MFMA tile; wave w handles code tiles 4w..4w+3
// (codes 128w..128w+127).  Grid = N/32 = 2048 blocks -> ~24 waves/CU.
// Loss uses the identity sum((q-x)^2) = sum_rows(||x||^2 + best_score).
// C/D layout: col = lane&31, row = (reg&3) + 8*(reg>>2) + 4*(lane>>5).
__global__ __launch_bounds__(256, 6)
void vq_main(const float* __restrict__ x,     // [N][D]
             const float* __restrict__ e_sq,  // [K]
             const float* __restrict__ e_t,   // [K][D] fp32
             const float* __restrict__ ef,    // f16 fragment buffer
             float* __restrict__ out_q,       // [N][D]
             float* __restrict__ out_idx,     // [N] (float)
             int*   __restrict__ cnt,         // [K] int histogram (rank source)
             int*   __restrict__ pk,          // [N] packed (rank<<9 | k)
             float* __restrict__ loss_parts)  // [32]
{
    __shared__ float sc_s[4][32];
    __shared__ int   id_s[4][32];
    __shared__ int   idx_f[32];

    const int tid  = threadIdx.x;
    const int w    = tid >> 6;
    const int l    = tid & 63;
    const int lr   = l & 31;       // A-row / B-col / C-col within tile
    const int hb   = l >> 5;       // k-group select
    const int row0 = blockIdx.x * 32;

    // ---- A fragments: lane supplies row (row0+lr), k = s*16 + hb*8 + j.
    // All 4 waves load the same 32 rows (L1-hit after first) + exact fp32 xsq.
    f16x8 ah[4], al[4];
    float xsq = 0.f;
    {
        const float* xr = x + (size_t)(row0 + lr) * D + hb * 8;
#pragma unroll
        for (int s = 0; s < 4; ++s) {
            float4 f0 = *(const float4*)(xr + s * 16);
            float4 f1 = *(const float4*)(xr + s * 16 + 4);
            float f[8] = {f0.x, f0.y, f0.z, f0.w, f1.x, f1.y, f1.z, f1.w};
#pragma unroll
            for (int j = 0; j < 8; ++j) {
                xsq = fmaf(f[j], f[j], xsq);
                _Float16 hv = (_Float16)f[j];
                ah[s][j] = hv;
                al[s][j] = (_Float16)(f[j] - (float)hv);
            }
        }
    }

    float best[16];
    int   bestk[16];
#pragma unroll
    for (int r = 0; r < 16; ++r) { best[r] = 3.0e38f; bestk[r] = 0; }

    const f16x8* __restrict__ efv = (const f16x8*)ef;

#pragma unroll 2
    for (int tt = 0; tt < 4; ++tt) {
        const int t = w * 4 + tt;           // global code tile
        f16x8 bh[4], bl[4];
#pragma unroll
        for (int s = 0; s < 4; ++s) {
            bh[s] = efv[(t * 8 + s * 2 + 0) * 64 + l];
            bl[s] = efv[(t * 8 + s * 2 + 1) * 64 + l];
        }
        f32x16 a0 = {}, a1 = {};
#pragma unroll
        for (int s = 0; s < 2; ++s) {
            a0 = __builtin_amdgcn_mfma_f32_32x32x16_f16(al[s], bh[s], a0, 0, 0, 0);
            a0 = __builtin_amdgcn_mfma_f32_32x32x16_f16(ah[s], bl[s], a0, 0, 0, 0);
            a0 = __builtin_amdgcn_mfma_f32_32x32x16_f16(ah[s], bh[s], a0, 0, 0, 0);
        }
#pragma unroll
        for (int s = 2; s < 4; ++s) {
            a1 = __builtin_amdgcn_mfma_f32_32x32x16_f16(al[s], bh[s], a1, 0, 0, 0);
            a1 = __builtin_amdgcn_mfma_f32_32x32x16_f16(ah[s], bl[s], a1, 0, 0, 0);
            a1 = __builtin_amdgcn_mfma_f32_32x32x16_f16(ah[s], bh[s], a1, 0, 0, 0);
        }
        f32x16 acc = a0 + a1;

        float eq = e_sq[t * 32 + lr];
        int   kc = t * 32 + lr;
#pragma unroll
        for (int r = 0; r < 16; ++r) {
            float sc = fmaf(-2.0f, acc[r], eq);
            if (sc < best[r]) { best[r] = sc; bestk[r] = kc; }  // k ascends with tt
        }
    }

    // ---- argmin reduce across the 32 lanes of each half (rows of this half)
#pragma unroll
    for (int r = 0; r < 16; ++r) {
        float b = best[r]; int bk = bestk[r];
#pragma unroll
        for (int m = 16; m >= 1; m >>= 1) {
            float ob  = __shfl_xor(b, m, 64);
            int   obk = __shfl_xor(bk, m, 64);
            if (ob < b || (ob == b && obk < bk)) { b = ob; bk = obk; }
        }
        if (lr == 0) {
            int row = (r & 3) + 8 * (r >> 2) + 4 * hb;
            sc_s[w][row] = b;
            id_s[w][row] = bk;
        }
    }

    // ---- exact ||x||^2 block total (wave 0 covers all 32 rows x both halves)
    float xs_total = 0.f;
    if (w == 0) {
        float xs = xsq;
#pragma unroll
        for (int m = 32; m >= 1; m >>= 1) xs += __shfl_xor(xs, m, 64);
        xs_total = xs;
    }
    __syncthreads();

    // ---- combine across waves (wave order = ascending k: strict < keeps
    // smallest k on ties, matching argmax-first semantics) + outputs
    if (tid < 32) {
        float b = sc_s[0][tid]; int bk = id_s[0][tid];
#pragma unroll
        for (int w2 = 1; w2 < 4; ++w2) {
            float ob = sc_s[w2][tid];
            int  obk = id_s[w2][tid];
            if (ob < b) { b = ob; bk = obk; }
        }
        idx_f[tid] = bk;
        out_idx[row0 + tid] = (float)bk;
        int rank = atomicAdd(&cnt[bk], 1);
        pk[row0 + tid] = (rank << 9) | bk;

        float lb = b;                      // sum of best scores over 32 rows
#pragma unroll
        for (int m = 16; m >= 1; m >>= 1) lb += __shfl_xor(lb, m, 64);
        if (tid == 0)
            atomicAdd(&loss_parts[blockIdx.x & 31], lb + xs_total);
    }
    __syncthreads();

    // ---- gather + out_q: wave w writes rows 8w..8w+7, lane = d -------------
#pragma unroll
    for (int rr = 0; rr < 8; ++rr) {
        const int row = w * 8 + rr;
        const int kk  = idx_f[row];
        out_q[(size_t)(row0 + row) * D + l] = e_t[kk * D + l];
    }
}

// ---------------- perm build: per-block redundant scan + scatter -------------
// 64 blocks x 512.  Each block scans the 512-entry histogram in LDS
// (Hillis-Steele), then scatters its 1024 rows: perm[offs[k]+rank] = row|k.
__global__ __launch_bounds__(512)
void vq_perm(const int* __restrict__ cnt,   // [K]
             const int* __restrict__ pk,    // [N] (rank<<9 | k)
             int* __restrict__ perm)        // [N] (row<<9 | k), k-sorted
{
    __shared__ int s[K];

    const int t = threadIdx.x;            // 0..511
    const int c0 = cnt[t];
    s[t] = c0;
    __syncthreads();
#pragma unroll
    for (int off = 1; off < K; off <<= 1) {
        int v = (t >= off) ? s[t - off] : 0;
        __syncthreads();
        s[t] += v;
        __syncthreads();
    }
    const int offs = s[t] - c0;           // exclusive prefix
    __syncthreads();
    s[t] = offs;
    __syncthreads();

#pragma unroll
    for (int it = 0; it < 2; ++it) {
        int row = blockIdx.x * 1024 + it * 512 + t;
        int v   = pk[row];
        int kk  = v & (K - 1);
        int rk  = v >> 9;
        perm[s[kk] + rk] = (row << 9) | kk;
    }
}

// ---------------- dw segmented reduce over k-sorted perm ---------------------
// 512 blocks x 256 = 2048 waves; wave w owns perm chunk [32w, 32w+32).
// lane = d.  k is wave-uniform per entry -> flush only at run boundaries.
__global__ __launch_bounds__(256, 2)
void vq_dwsum(const int* __restrict__ perm,  // [N] (row<<9 | k)
              const float* __restrict__ x,   // [N][D]
              float* __restrict__ dw_t)      // [K][D] accumulate
{
    const int w = (blockIdx.x * 256 + threadIdx.x) >> 6;  // 0..2047
    const int l = threadIdx.x & 63;

    int pv = 0;
    if (l < 32) pv = perm[w * 32 + l];

    float sum = 0.f;
    int kcur = -1;
#pragma unroll
    for (int e = 0; e < 32; ++e) {
        int pe  = __shfl(pv, e, 64);
        int kk  = pe & (K - 1);
        int row = pe >> 9;
        float xv = x[(size_t)row * D + l];
        if (kk != kcur) {                       // wave-uniform branch
            if (kcur >= 0) atomicAdd(&dw_t[kcur * D + l], sum);
            kcur = kk; sum = xv;
        } else {
            sum += xv;
        }
    }
    atomicAdd(&dw_t[kcur * D + l], sum);
}

// ---------------- finalize: scalars + hdw + new embeddings -------------------
// 128 blocks x 256.  Every block redundantly recomputes debias and the
// n-reduction from the histogram (2KB, L2-resident).
__global__ __launch_bounds__(256)
void vq_final(const int*   __restrict__ cnt,         // [K]
              const float* __restrict__ loss_parts,  // [32]
              const float* __restrict__ ema_csh,     // [K]
              const int*   __restrict__ counter,
              const float* __restrict__ ema_dwh,     // [D][K]
              const float* __restrict__ dw_t,        // [K][D]
              float* __restrict__ out_loss,
              float* __restrict__ out_perp,
              float* __restrict__ out_hcs,           // [K]
              float* __restrict__ out_nemb,          // [D][K]
              float* __restrict__ out_hdw)           // [D][K]
{
    __shared__ float s_red[4];
    __shared__ float s_n;

    const int tid = threadIdx.x;
    const int b   = blockIdx.x;

    const int   cntr   = counter[0] + 1;
    const float debias = 1.0f - powf(DECAY, (float)cntr);

    const float c0 = (float)cnt[tid];
    const float c1 = (float)cnt[tid + 256];
    const float hid0 = ema_csh[tid] * DECAY + c0 * ONE_MINUS_DECAY;
    const float hid1 = ema_csh[tid + 256] * DECAY + c1 * ONE_MINUS_DECAY;
    const float upd0 = hid0 / debias;
    const float upd1 = hid1 / debias;

    float v = upd0 + upd1;
#pragma unroll
    for (int m = 32; m >= 1; m >>= 1) v += __shfl_xor(v, m, 64);
    if ((tid & 63) == 0) s_red[tid >> 6] = v;
    __syncthreads();
    if (tid == 0) s_n = s_red[0] + s_red[1] + s_red[2] + s_red[3];
    __syncthreads();
    const float n = s_n;

    const int i  = b * 256 + tid;          // 0..32767
    const int kk = i & (K - 1);
    const int d  = i >> 9;
    const float updk   = (b & 1) ? upd1 : upd0;
    const float stable = (updk + 1e-5f) / (n + (float)K * 1e-5f) * n;
    const float hdw = ema_dwh[i] * DECAY + dw_t[kk * D + d] * ONE_MINUS_DECAY;
    out_hdw[i]  = hdw;
    out_nemb[i] = (hdw / debias) / stable;

    if (b == 0) {
        out_hcs[tid]       = hid0;
        out_hcs[tid + 256] = hid1;

        const float inv = 1.0f / (float)NROWS;
        float p0 = c0 * inv, p1 = c1 * inv;
        float ve = p0 * logf(p0 + 1e-10f) + p1 * logf(p1 + 1e-10f);
#pragma unroll
        for (int m = 32; m >= 1; m >>= 1) ve += __shfl_xor(ve, m, 64);
        __syncthreads();
        if ((tid & 63) == 0) s_red[tid >> 6] = ve;
        __syncthreads();
        if (tid < 32) {
            float lp = loss_parts[tid];
#pragma unroll
            for (int m = 16; m >= 1; m >>= 1) lp += __shfl_xor(lp, m, 64);
            if (tid == 0) {
                out_loss[0] = COMMIT * lp / (float)((size_t)NROWS * D);
                out_perp[0] = expf(-(s_red[0] + s_red[1] + s_red[2] + s_red[3]));
            }
        }
    }
}

// ---------------- launch ------------------------------------------------------
extern "C" void kernel_launch(void* const* d_in, const int* in_sizes, int n_in,
                              void* d_out, int out_size, void* d_ws, size_t ws_size,
                              hipStream_t stream)
{
    const float* x_in    = (const float*)d_in[0];   // [64,32,32,64]
    const float* emb     = (const float*)d_in[1];   // [64,512]
    const float* ema_csh = (const float*)d_in[2];   // [512]
    const float* ema_dwh = (const float*)d_in[3];   // [64,512]
    const int*   counter = (const int*)d_in[4];     // [1]

    float* ws  = (float*)d_ws;
    float* out = (float*)d_out;

    vq_prep<<<128, 256, 0, stream>>>(emb, ws);

    vq_main<<<NROWS / 32, 256, 0, stream>>>(
        x_in, ws + WS_ESQ, ws + WS_ET, ws + WS_EF,
        out + OUT_Q, out + OUT_IDX,
        (int*)(ws + WS_CNT), (int*)(ws + WS_PK), ws + WS_LPART);

    vq_perm<<<64, 512, 0, stream>>>(
        (const int*)(ws + WS_CNT), (const int*)(ws + WS_PK),
        (int*)(ws + WS_PERM));

    vq_dwsum<<<512, 256, 0, stream>>>(
        (const int*)(ws + WS_PERM), x_in, ws + WS_DWT);

    vq_final<<<128, 256, 0, stream>>>(
        (const int*)(ws + WS_CNT), ws + WS_LPART, ema_csh, counter,
        ema_dwh, ws + WS_DWT,
        out + OUT_LOSS, out + OUT_PERP, out + OUT_HCS,
        out + OUT_NEMB, out + OUT_HDW);
}

// Round 5
// 157.329 us; speedup vs baseline: 1.4932x; 1.4932x over previous
//
#include <hip/hip_runtime.h>
#include <math.h>

// Problem constants
#define D 64
#define K 512
#define NROWS 65536
#define DECAY 0.99f
#define ONE_MINUS_DECAY (1.0f - 0.99f)
#define COMMIT 0.25f

// ws layout (float offsets)
#define WS_DWT    0              // [K][D] = 32768 floats, dw accumulator (zeroed)
#define WS_CNT    32768          // [K] int histogram / rank counters (zeroed)
#define WS_LPART  33280          // [32] loss partial sums (zeroed)
#define WS_ZERO4  8336           // float4 count zeroed by prep (33344 floats)
#define WS_ESQ    33344          // [K]   ||e_k||^2
#define WS_ET     33856          // [K][D] fp32 embeddings transposed (gather)
#define WS_EF     66624          // f16 MFMA B-fragments: 8192 x 16B = 32768 floats
#define WS_PK     99392          // [N] int packed (rank<<9 | k)
#define WS_PERM   164928         // [N] int packed (row<<9 | k)

// out layout (float offsets) — unchanged
#define OUT_Q     0
#define OUT_LOSS  4194304
#define OUT_PERP  4194305
#define OUT_IDX   4194306
#define OUT_NEMB  4259842
#define OUT_HCS   4292610
#define OUT_HDW   4293122

typedef _Float16 f16x8 __attribute__((ext_vector_type(8)));
typedef float    f32x16 __attribute__((ext_vector_type(16)));

// ---------------- prep: zero accum + e_t + ||e||^2 + f16 hi/lo B-fragments ---
// B-fragment layout for v_mfma_f32_32x32x16_f16:
//   lane l supplies col = tile*32 + (l&31), k = (l>>5)*8 + j (j=0..7)
// fragment block index i = ((t*4 + s)*2 + h)*64 + l  (s=kstep, h=0 hi / 1 lo)
__global__ void vq_prep(const float* __restrict__ emb,  // [D][K]
                        float* __restrict__ ws)
{
    int i = blockIdx.x * 256 + threadIdx.x;   // 0..32767 (128 blocks)
    if (i < WS_ZERO4) {                       // zero dw_t + cnt + loss parts
        ((float4*)ws)[i] = make_float4(0.f, 0.f, 0.f, 0.f);
    }
    if (i < K * D) {                          // e_t[k][d] = emb[d][k]
        int k = i >> 6, d = i & 63;
        ws[WS_ET + i] = emb[d * K + k];
    }
    if (i < K) {                              // ||e_k||^2
        float s = 0.f;
        for (int d = 0; d < D; ++d) { float v = emb[d * K + i]; s += v * v; }
        ws[WS_ESQ + i] = s;
    }
    if (i < 8192) {                           // f16 hi/lo fragment buffer
        int l = i & 63, h = (i >> 6) & 1, s = (i >> 7) & 3, t = i >> 9;
        int col = t * 32 + (l & 31);
        int d0  = s * 16 + ((l >> 5) << 3);
        f16x8 frag;
#pragma unroll
        for (int j = 0; j < 8; ++j) {
            float v = emb[(d0 + j) * K + col];
            _Float16 hv = (_Float16)v;
            frag[j] = h ? (_Float16)(v - (float)hv) : hv;
        }
        ((f16x8*)(ws + WS_EF))[i] = frag;
    }
}

// ---------------- main: MFMA distances, K-split x4 across waves --------------
// Block = 4 waves = ONE 32-row MFMA tile; wave w handles code tiles 4w..4w+3
// (codes 128w..128w+127).  Grid = N/32 = 2048 blocks.
// __launch_bounds__(256,4): 128-VGPR budget — round-4's (256,6) capped the
// allocator at 40 VGPRs and spilled ~150 dwords/thread to scratch
// (FETCH 186MB / WRITE 321MB of pure spill traffic).  The ~70-reg body fits
// under 128 with zero spill; occupancy is then VGPR-limited at ~6-7 waves/EU.
// Loss uses the identity sum((q-x)^2) = sum_rows(||x||^2 + best_score).
// C/D layout: col = lane&31, row = (reg&3) + 8*(reg>>2) + 4*(lane>>5).
__global__ __launch_bounds__(256, 4)
void vq_main(const float* __restrict__ x,     // [N][D]
             const float* __restrict__ e_sq,  // [K]
             const float* __restrict__ e_t,   // [K][D] fp32
             const float* __restrict__ ef,    // f16 fragment buffer
             float* __restrict__ out_q,       // [N][D]
             float* __restrict__ out_idx,     // [N] (float)
             int*   __restrict__ cnt,         // [K] int histogram (rank source)
             int*   __restrict__ pk,          // [N] packed (rank<<9 | k)
             float* __restrict__ loss_parts)  // [32]
{
    __shared__ float sc_s[4][32];
    __shared__ int   id_s[4][32];
    __shared__ int   idx_f[32];

    const int tid  = threadIdx.x;
    const int w    = tid >> 6;
    const int l    = tid & 63;
    const int lr   = l & 31;       // A-row / B-col / C-col within tile
    const int hb   = l >> 5;       // k-group select
    const int row0 = blockIdx.x * 32;

    // ---- A fragments: lane supplies row (row0+lr), k = s*16 + hb*8 + j.
    // All 4 waves load the same 32 rows (L1-hit after first) + exact fp32 xsq.
    f16x8 ah[4], al[4];
    float xsq = 0.f;
    {
        const float* xr = x + (size_t)(row0 + lr) * D + hb * 8;
#pragma unroll
        for (int s = 0; s < 4; ++s) {
            float4 f0 = *(const float4*)(xr + s * 16);
            float4 f1 = *(const float4*)(xr + s * 16 + 4);
            float f[8] = {f0.x, f0.y, f0.z, f0.w, f1.x, f1.y, f1.z, f1.w};
#pragma unroll
            for (int j = 0; j < 8; ++j) {
                xsq = fmaf(f[j], f[j], xsq);
                _Float16 hv = (_Float16)f[j];
                ah[s][j] = hv;
                al[s][j] = (_Float16)(f[j] - (float)hv);
            }
        }
    }

    float best[16];
    int   bestk[16];
#pragma unroll
    for (int r = 0; r < 16; ++r) { best[r] = 3.0e38f; bestk[r] = 0; }

    const f16x8* __restrict__ efv = (const f16x8*)ef;

#pragma unroll 2
    for (int tt = 0; tt < 4; ++tt) {
        const int t = w * 4 + tt;           // global code tile
        f16x8 bh[4], bl[4];
#pragma unroll
        for (int s = 0; s < 4; ++s) {
            bh[s] = efv[(t * 8 + s * 2 + 0) * 64 + l];
            bl[s] = efv[(t * 8 + s * 2 + 1) * 64 + l];
        }
        f32x16 a0 = {}, a1 = {};
#pragma unroll
        for (int s = 0; s < 2; ++s) {
            a0 = __builtin_amdgcn_mfma_f32_32x32x16_f16(al[s], bh[s], a0, 0, 0, 0);
            a0 = __builtin_amdgcn_mfma_f32_32x32x16_f16(ah[s], bl[s], a0, 0, 0, 0);
            a0 = __builtin_amdgcn_mfma_f32_32x32x16_f16(ah[s], bh[s], a0, 0, 0, 0);
        }
#pragma unroll
        for (int s = 2; s < 4; ++s) {
            a1 = __builtin_amdgcn_mfma_f32_32x32x16_f16(al[s], bh[s], a1, 0, 0, 0);
            a1 = __builtin_amdgcn_mfma_f32_32x32x16_f16(ah[s], bl[s], a1, 0, 0, 0);
            a1 = __builtin_amdgcn_mfma_f32_32x32x16_f16(ah[s], bh[s], a1, 0, 0, 0);
        }
        f32x16 acc = a0 + a1;

        float eq = e_sq[t * 32 + lr];
        int   kc = t * 32 + lr;
#pragma unroll
        for (int r = 0; r < 16; ++r) {
            float sc = fmaf(-2.0f, acc[r], eq);
            if (sc < best[r]) { best[r] = sc; bestk[r] = kc; }  // k ascends with tt
        }
    }

    // ---- argmin reduce across the 32 lanes of each half (rows of this half)
#pragma unroll
    for (int r = 0; r < 16; ++r) {
        float b = best[r]; int bk = bestk[r];
#pragma unroll
        for (int m = 16; m >= 1; m >>= 1) {
            float ob  = __shfl_xor(b, m, 64);
            int   obk = __shfl_xor(bk, m, 64);
            if (ob < b || (ob == b && obk < bk)) { b = ob; bk = obk; }
        }
        if (lr == 0) {
            int row = (r & 3) + 8 * (r >> 2) + 4 * hb;
            sc_s[w][row] = b;
            id_s[w][row] = bk;
        }
    }

    // ---- exact ||x||^2 block total (wave 0 covers all 32 rows x both halves)
    float xs_total = 0.f;
    if (w == 0) {
        float xs = xsq;
#pragma unroll
        for (int m = 32; m >= 1; m >>= 1) xs += __shfl_xor(xs, m, 64);
        xs_total = xs;
    }
    __syncthreads();

    // ---- combine across waves (wave order = ascending k: strict < keeps
    // smallest k on ties, matching argmax-first semantics) + outputs
    if (tid < 32) {
        float b = sc_s[0][tid]; int bk = id_s[0][tid];
#pragma unroll
        for (int w2 = 1; w2 < 4; ++w2) {
            float ob = sc_s[w2][tid];
            int  obk = id_s[w2][tid];
            if (ob < b) { b = ob; bk = obk; }
        }
        idx_f[tid] = bk;
        out_idx[row0 + tid] = (float)bk;
        int rank = atomicAdd(&cnt[bk], 1);
        pk[row0 + tid] = (rank << 9) | bk;

        float lb = b;                      // sum of best scores over 32 rows
#pragma unroll
        for (int m = 16; m >= 1; m >>= 1) lb += __shfl_xor(lb, m, 64);
        if (tid == 0)
            atomicAdd(&loss_parts[blockIdx.x & 31], lb + xs_total);
    }
    __syncthreads();

    // ---- gather + out_q: wave w writes rows 8w..8w+7, lane = d -------------
#pragma unroll
    for (int rr = 0; rr < 8; ++rr) {
        const int row = w * 8 + rr;
        const int kk  = idx_f[row];
        out_q[(size_t)(row0 + row) * D + l] = e_t[kk * D + l];
    }
}

// ---------------- perm build: per-block redundant scan + scatter -------------
// 64 blocks x 512.  Each block scans the 512-entry histogram in LDS
// (Hillis-Steele), then scatters its 1024 rows: perm[offs[k]+rank] = row|k.
__global__ __launch_bounds__(512)
void vq_perm(const int* __restrict__ cnt,   // [K]
             const int* __restrict__ pk,    // [N] (rank<<9 | k)
             int* __restrict__ perm)        // [N] (row<<9 | k), k-sorted
{
    __shared__ int s[K];

    const int t = threadIdx.x;            // 0..511
    const int c0 = cnt[t];
    s[t] = c0;
    __syncthreads();
#pragma unroll
    for (int off = 1; off < K; off <<= 1) {
        int v = (t >= off) ? s[t - off] : 0;
        __syncthreads();
        s[t] += v;
        __syncthreads();
    }
    const int offs = s[t] - c0;           // exclusive prefix
    __syncthreads();
    s[t] = offs;
    __syncthreads();

#pragma unroll
    for (int it = 0; it < 2; ++it) {
        int row = blockIdx.x * 1024 + it * 512 + t;
        int v   = pk[row];
        int kk  = v & (K - 1);
        int rk  = v >> 9;
        perm[s[kk] + rk] = (row << 9) | kk;
    }
}

// ---------------- dw segmented reduce over k-sorted perm ---------------------
// 512 blocks x 256 = 2048 waves; wave w owns perm chunk [32w, 32w+32).
// lane = d.  k is wave-uniform per entry -> flush only at run boundaries.
__global__ __launch_bounds__(256, 2)
void vq_dwsum(const int* __restrict__ perm,  // [N] (row<<9 | k)
              const float* __restrict__ x,   // [N][D]
              float* __restrict__ dw_t)      // [K][D] accumulate
{
    const int w = (blockIdx.x * 256 + threadIdx.x) >> 6;  // 0..2047
    const int l = threadIdx.x & 63;

    int pv = 0;
    if (l < 32) pv = perm[w * 32 + l];

    float sum = 0.f;
    int kcur = -1;
#pragma unroll
    for (int e = 0; e < 32; ++e) {
        int pe  = __shfl(pv, e, 64);
        int kk  = pe & (K - 1);
        int row = pe >> 9;
        float xv = x[(size_t)row * D + l];
        if (kk != kcur) {                       // wave-uniform branch
            if (kcur >= 0) atomicAdd(&dw_t[kcur * D + l], sum);
            kcur = kk; sum = xv;
        } else {
            sum += xv;
        }
    }
    atomicAdd(&dw_t[kcur * D + l], sum);
}

// ---------------- finalize: scalars + hdw + new embeddings -------------------
// 128 blocks x 256.  Every block redundantly recomputes debias and the
// n-reduction from the histogram (2KB, L2-resident).
__global__ __launch_bounds__(256)
void vq_final(const int*   __restrict__ cnt,         // [K]
              const float* __restrict__ loss_parts,  // [32]
              const float* __restrict__ ema_csh,     // [K]
              const int*   __restrict__ counter,
              const float* __restrict__ ema_dwh,     // [D][K]
              const float* __restrict__ dw_t,        // [K][D]
              float* __restrict__ out_loss,
              float* __restrict__ out_perp,
              float* __restrict__ out_hcs,           // [K]
              float* __restrict__ out_nemb,          // [D][K]
              float* __restrict__ out_hdw)           // [D][K]
{
    __shared__ float s_red[4];
    __shared__ float s_n;

    const int tid = threadIdx.x;
    const int b   = blockIdx.x;

    const int   cntr   = counter[0] + 1;
    const float debias = 1.0f - powf(DECAY, (float)cntr);

    const float c0 = (float)cnt[tid];
    const float c1 = (float)cnt[tid + 256];
    const float hid0 = ema_csh[tid] * DECAY + c0 * ONE_MINUS_DECAY;
    const float hid1 = ema_csh[tid + 256] * DECAY + c1 * ONE_MINUS_DECAY;
    const float upd0 = hid0 / debias;
    const float upd1 = hid1 / debias;

    float v = upd0 + upd1;
#pragma unroll
    for (int m = 32; m >= 1; m >>= 1) v += __shfl_xor(v, m, 64);
    if ((tid & 63) == 0) s_red[tid >> 6] = v;
    __syncthreads();
    if (tid == 0) s_n = s_red[0] + s_red[1] + s_red[2] + s_red[3];
    __syncthreads();
    const float n = s_n;

    const int i  = b * 256 + tid;          // 0..32767
    const int kk = i & (K - 1);
    const int d  = i >> 9;
    const float updk   = (b & 1) ? upd1 : upd0;
    const float stable = (updk + 1e-5f) / (n + (float)K * 1e-5f) * n;
    const float hdw = ema_dwh[i] * DECAY + dw_t[kk * D + d] * ONE_MINUS_DECAY;
    out_hdw[i]  = hdw;
    out_nemb[i] = (hdw / debias) / stable;

    if (b == 0) {
        out_hcs[tid]       = hid0;
        out_hcs[tid + 256] = hid1;

        const float inv = 1.0f / (float)NROWS;
        float p0 = c0 * inv, p1 = c1 * inv;
        float ve = p0 * logf(p0 + 1e-10f) + p1 * logf(p1 + 1e-10f);
#pragma unroll
        for (int m = 32; m >= 1; m >>= 1) ve += __shfl_xor(ve, m, 64);
        __syncthreads();
        if ((tid & 63) == 0) s_red[tid >> 6] = ve;
        __syncthreads();
        if (tid < 32) {
            float lp = loss_parts[tid];
#pragma unroll
            for (int m = 16; m >= 1; m >>= 1) lp += __shfl_xor(lp, m, 64);
            if (tid == 0) {
                out_loss[0] = COMMIT * lp / (float)((size_t)NROWS * D);
                out_perp[0] = expf(-(s_red[0] + s_red[1] + s_red[2] + s_red[3]));
            }
        }
    }
}

// ---------------- launch ------------------------------------------------------
extern "C" void kernel_launch(void* const* d_in, const int* in_sizes, int n_in,
                              void* d_out, int out_size, void* d_ws, size_t ws_size,
                              hipStream_t stream)
{
    const float* x_in    = (const float*)d_in[0];   // [64,32,32,64]
    const float* emb     = (const float*)d_in[1];   // [64,512]
    const float* ema_csh = (const float*)d_in[2];   // [512]
    const float* ema_dwh = (const float*)d_in[3];   // [64,512]
    const int*   counter = (const int*)d_in[4];     // [1]

    float* ws  = (float*)d_ws;
    float* out = (float*)d_out;

    vq_prep<<<128, 256, 0, stream>>>(emb, ws);

    vq_main<<<NROWS / 32, 256, 0, stream>>>(
        x_in, ws + WS_ESQ, ws + WS_ET, ws + WS_EF,
        out + OUT_Q, out + OUT_IDX,
        (int*)(ws + WS_CNT), (int*)(ws + WS_PK), ws + WS_LPART);

    vq_perm<<<64, 512, 0, stream>>>(
        (const int*)(ws + WS_CNT), (const int*)(ws + WS_PK),
        (int*)(ws + WS_PERM));

    vq_dwsum<<<512, 256, 0, stream>>>(
        (const int*)(ws + WS_PERM), x_in, ws + WS_DWT);

    vq_final<<<128, 256, 0, stream>>>(
        (const int*)(ws + WS_CNT), ws + WS_LPART, ema_csh, counter,
        ema_dwh, ws + WS_DWT,
        out + OUT_LOSS, out + OUT_PERP, out + OUT_HCS,
        out + OUT_NEMB, out + OUT_HDW);
}

// Round 6
// 151.695 us; speedup vs baseline: 1.5486x; 1.0371x over previous
//
#include <hip/hip_runtime.h>
#include <math.h>

// Problem constants
#define D 64
#define K 512
#define NROWS 65536
#define DECAY 0.99f
#define ONE_MINUS_DECAY (1.0f - 0.99f)
#define COMMIT 0.25f

// ws layout (float offsets)
#define WS_DWT    0              // [K][D] = 32768 floats, dw accumulator (zeroed)
#define WS_CNT    32768          // [K] int histogram / rank counters (zeroed)
#define WS_LPART  33280          // [32] loss partial sums (zeroed)
#define WS_ZERO4  8336           // float4 count zeroed by prep (33344 floats)
#define WS_ESQ    33344          // [K]   ||e_k||^2
#define WS_ET     33856          // [K][D] fp32 embeddings transposed (gather)
#define WS_EF     66624          // f16 MFMA B-fragments: 8192 x 16B = 32768 floats
#define WS_PK     99392          // [N] int packed (rank<<9 | k)
#define WS_PERM   164928         // [N] int packed (row<<9 | k)

// out layout (float offsets) — unchanged
#define OUT_Q     0
#define OUT_LOSS  4194304
#define OUT_PERP  4194305
#define OUT_IDX   4194306
#define OUT_NEMB  4259842
#define OUT_HCS   4292610
#define OUT_HDW   4293122

typedef _Float16 f16x8 __attribute__((ext_vector_type(8)));
typedef float    f32x16 __attribute__((ext_vector_type(16)));

// ---------------- prep: zero accum + e_t + ||e||^2 + f16 hi/lo B-fragments ---
// B-fragment layout for v_mfma_f32_32x32x16_f16:
//   lane l supplies col = tile*32 + (l&31), k = (l>>5)*8 + j (j=0..7)
// fragment block index i = ((t*4 + s)*2 + h)*64 + l  (s=kstep, h=0 hi / 1 lo)
__global__ void vq_prep(const float* __restrict__ emb,  // [D][K]
                        float* __restrict__ ws)
{
    int i = blockIdx.x * 256 + threadIdx.x;   // 0..32767 (128 blocks)
    if (i < WS_ZERO4) {                       // zero dw_t + cnt + loss parts
        ((float4*)ws)[i] = make_float4(0.f, 0.f, 0.f, 0.f);
    }
    if (i < K * D) {                          // e_t[k][d] = emb[d][k]
        int k = i >> 6, d = i & 63;
        ws[WS_ET + i] = emb[d * K + k];
    }
    if (i < K) {                              // ||e_k||^2
        float s = 0.f;
        for (int d = 0; d < D; ++d) { float v = emb[d * K + i]; s += v * v; }
        ws[WS_ESQ + i] = s;
    }
    if (i < 8192) {                           // f16 hi/lo fragment buffer
        int l = i & 63, h = (i >> 6) & 1, s = (i >> 7) & 3, t = i >> 9;
        int col = t * 32 + (l & 31);
        int d0  = s * 16 + ((l >> 5) << 3);
        f16x8 frag;
#pragma unroll
        for (int j = 0; j < 8; ++j) {
            float v = emb[(d0 + j) * K + col];
            _Float16 hv = (_Float16)v;
            frag[j] = h ? (_Float16)(v - (float)hv) : hv;
        }
        ((f16x8*)(ws + WS_EF))[i] = frag;
    }
}

// ---------------- main: MFMA distances, K-split x4 across waves --------------
// Block = 4 waves = ONE 32-row MFMA tile; wave w handles code tiles 4w..4w+3.
// Register-footprint discipline (round-5 spilled ~140B/thread at (256,4)):
//   * SINGLE f32x16 accumulator chain            (A 32 + acc 16)
//   * per-kstep B-fragment loads (8 live regs, consumed immediately)
//   * bestk packed as 2-bit tile fields in ONE uint32 (k = (w*4+tt)*32+lr);
//     best[] update is a pure v_min_f32, strict-< cndmask on the pack keeps
//     smallest-k tie-break.
// Total ~92 VGPRs -> fits the 128 cap of (256,4) with margin, zero spill.
// Loss identity: sum((q-x)^2) = sum_rows(||x||^2 + best_score).
// C/D layout: col = lane&31, row = (reg&3) + 8*(reg>>2) + 4*(lane>>5).
__global__ __launch_bounds__(256, 4)
void vq_main(const float* __restrict__ x,     // [N][D]
             const float* __restrict__ e_sq,  // [K]
             const float* __restrict__ e_t,   // [K][D] fp32
             const float* __restrict__ ef,    // f16 fragment buffer
             float* __restrict__ out_q,       // [N][D]
             float* __restrict__ out_idx,     // [N] (float)
             int*   __restrict__ cnt,         // [K] int histogram (rank source)
             int*   __restrict__ pk,          // [N] packed (rank<<9 | k)
             float* __restrict__ loss_parts)  // [32]
{
    __shared__ float sc_s[4][32];
    __shared__ int   id_s[4][32];
    __shared__ int   idx_f[32];

    const int tid  = threadIdx.x;
    const int w    = tid >> 6;
    const int l    = tid & 63;
    const int lr   = l & 31;       // A-row / B-col / C-col within tile
    const int hb   = l >> 5;       // k-group select
    const int row0 = blockIdx.x * 32;

    // ---- A fragments: lane supplies row (row0+lr), k = s*16 + hb*8 + j.
    // All 4 waves load the same 32 rows (L1-hit after first) + exact fp32 xsq.
    f16x8 ah[4], al[4];
    float xsq = 0.f;
    {
        const float* xr = x + (size_t)(row0 + lr) * D + hb * 8;
#pragma unroll
        for (int s = 0; s < 4; ++s) {
            float4 f0 = *(const float4*)(xr + s * 16);
            float4 f1 = *(const float4*)(xr + s * 16 + 4);
            float f[8] = {f0.x, f0.y, f0.z, f0.w, f1.x, f1.y, f1.z, f1.w};
#pragma unroll
            for (int j = 0; j < 8; ++j) {
                xsq = fmaf(f[j], f[j], xsq);
                _Float16 hv = (_Float16)f[j];
                ah[s][j] = hv;
                al[s][j] = (_Float16)(f[j] - (float)hv);
            }
        }
    }

    float    best[16];
    unsigned pack = 0u;            // 2-bit best-tile index per acc reg
#pragma unroll
    for (int r = 0; r < 16; ++r) best[r] = 3.0e38f;

    const f16x8* __restrict__ efv = (const f16x8*)ef;

#pragma unroll 2
    for (int tt = 0; tt < 4; ++tt) {
        const int t = w * 4 + tt;           // global code tile
        f32x16 acc = {};
#pragma unroll
        for (int s = 0; s < 4; ++s) {
            f16x8 bh = efv[(t * 8 + s * 2 + 0) * 64 + l];
            f16x8 bl = efv[(t * 8 + s * 2 + 1) * 64 + l];
            acc = __builtin_amdgcn_mfma_f32_32x32x16_f16(al[s], bh, acc, 0, 0, 0);
            acc = __builtin_amdgcn_mfma_f32_32x32x16_f16(ah[s], bl, acc, 0, 0, 0);
            acc = __builtin_amdgcn_mfma_f32_32x32x16_f16(ah[s], bh, acc, 0, 0, 0);
        }

        const float eq = e_sq[t * 32 + lr];
#pragma unroll
        for (int r = 0; r < 16; ++r) {
            float sc = fmaf(-2.0f, acc[r], eq);
            bool better = sc < best[r];             // strict: earlier (smaller
            unsigned nb = (pack & ~(3u << (2 * r))) // k) tile wins ties
                        | ((unsigned)tt << (2 * r));
            best[r] = better ? sc : best[r];        // == v_min_f32
            pack    = better ? nb : pack;
        }
    }

    // ---- argmin reduce across the 32 lanes of each half (rows of this half)
#pragma unroll
    for (int r = 0; r < 16; ++r) {
        float b  = best[r];
        int   bk = (w * 4 + (int)((pack >> (2 * r)) & 3u)) * 32 + lr;
#pragma unroll
        for (int m = 16; m >= 1; m >>= 1) {
            float ob  = __shfl_xor(b, m, 64);
            int   obk = __shfl_xor(bk, m, 64);
            if (ob < b || (ob == b && obk < bk)) { b = ob; bk = obk; }
        }
        if (lr == 0) {
            int row = (r & 3) + 8 * (r >> 2) + 4 * hb;
            sc_s[w][row] = b;
            id_s[w][row] = bk;
        }
    }

    // ---- exact ||x||^2 block total (wave 0 covers all 32 rows x both halves)
    float xs_total = 0.f;
    if (w == 0) {
        float xs = xsq;
#pragma unroll
        for (int m = 32; m >= 1; m >>= 1) xs += __shfl_xor(xs, m, 64);
        xs_total = xs;
    }
    __syncthreads();

    // ---- combine across waves (wave order = ascending k: strict < keeps
    // smallest k on ties, matching argmax-first semantics) + outputs
    if (tid < 32) {
        float b = sc_s[0][tid]; int bk = id_s[0][tid];
#pragma unroll
        for (int w2 = 1; w2 < 4; ++w2) {
            float ob = sc_s[w2][tid];
            int  obk = id_s[w2][tid];
            if (ob < b) { b = ob; bk = obk; }
        }
        idx_f[tid] = bk;
        out_idx[row0 + tid] = (float)bk;
        int rank = atomicAdd(&cnt[bk], 1);
        pk[row0 + tid] = (rank << 9) | bk;

        float lb = b;                      // sum of best scores over 32 rows
#pragma unroll
        for (int m = 16; m >= 1; m >>= 1) lb += __shfl_xor(lb, m, 64);
        if (tid == 0)
            atomicAdd(&loss_parts[blockIdx.x & 31], lb + xs_total);
    }
    __syncthreads();

    // ---- gather + out_q: wave w writes rows 8w..8w+7, lane = d -------------
#pragma unroll
    for (int rr = 0; rr < 8; ++rr) {
        const int row = w * 8 + rr;
        const int kk  = idx_f[row];
        out_q[(size_t)(row0 + row) * D + l] = e_t[kk * D + l];
    }
}

// ---------------- perm build: per-block redundant scan + scatter -------------
// 64 blocks x 512.  Each block scans the 512-entry histogram in LDS
// (Hillis-Steele), then scatters its 1024 rows: perm[offs[k]+rank] = row|k.
__global__ __launch_bounds__(512)
void vq_perm(const int* __restrict__ cnt,   // [K]
             const int* __restrict__ pk,    // [N] (rank<<9 | k)
             int* __restrict__ perm)        // [N] (row<<9 | k), k-sorted
{
    __shared__ int s[K];

    const int t = threadIdx.x;            // 0..511
    const int c0 = cnt[t];
    s[t] = c0;
    __syncthreads();
#pragma unroll
    for (int off = 1; off < K; off <<= 1) {
        int v = (t >= off) ? s[t - off] : 0;
        __syncthreads();
        s[t] += v;
        __syncthreads();
    }
    const int offs = s[t] - c0;           // exclusive prefix
    __syncthreads();
    s[t] = offs;
    __syncthreads();

#pragma unroll
    for (int it = 0; it < 2; ++it) {
        int row = blockIdx.x * 1024 + it * 512 + t;
        int v   = pk[row];
        int kk  = v & (K - 1);
        int rk  = v >> 9;
        perm[s[kk] + rk] = (row << 9) | kk;
    }
}

// ---------------- dw segmented reduce over k-sorted perm ---------------------
// 512 blocks x 256 = 2048 waves; wave w owns perm chunk [32w, 32w+32).
// lane = d.  k is wave-uniform per entry -> flush only at run boundaries.
__global__ __launch_bounds__(256, 2)
void vq_dwsum(const int* __restrict__ perm,  // [N] (row<<9 | k)
              const float* __restrict__ x,   // [N][D]
              float* __restrict__ dw_t)      // [K][D] accumulate
{
    const int w = (blockIdx.x * 256 + threadIdx.x) >> 6;  // 0..2047
    const int l = threadIdx.x & 63;

    int pv = 0;
    if (l < 32) pv = perm[w * 32 + l];

    float sum = 0.f;
    int kcur = -1;
#pragma unroll
    for (int e = 0; e < 32; ++e) {
        int pe  = __shfl(pv, e, 64);
        int kk  = pe & (K - 1);
        int row = pe >> 9;
        float xv = x[(size_t)row * D + l];
        if (kk != kcur) {                       // wave-uniform branch
            if (kcur >= 0) atomicAdd(&dw_t[kcur * D + l], sum);
            kcur = kk; sum = xv;
        } else {
            sum += xv;
        }
    }
    atomicAdd(&dw_t[kcur * D + l], sum);
}

// ---------------- finalize: scalars + hdw + new embeddings -------------------
// 128 blocks x 256.  Every block redundantly recomputes debias and the
// n-reduction from the histogram (2KB, L2-resident).
__global__ __launch_bounds__(256)
void vq_final(const int*   __restrict__ cnt,         // [K]
              const float* __restrict__ loss_parts,  // [32]
              const float* __restrict__ ema_csh,     // [K]
              const int*   __restrict__ counter,
              const float* __restrict__ ema_dwh,     // [D][K]
              const float* __restrict__ dw_t,        // [K][D]
              float* __restrict__ out_loss,
              float* __restrict__ out_perp,
              float* __restrict__ out_hcs,           // [K]
              float* __restrict__ out_nemb,          // [D][K]
              float* __restrict__ out_hdw)           // [D][K]
{
    __shared__ float s_red[4];
    __shared__ float s_n;

    const int tid = threadIdx.x;
    const int b   = blockIdx.x;

    const int   cntr   = counter[0] + 1;
    const float debias = 1.0f - powf(DECAY, (float)cntr);

    const float c0 = (float)cnt[tid];
    const float c1 = (float)cnt[tid + 256];
    const float hid0 = ema_csh[tid] * DECAY + c0 * ONE_MINUS_DECAY;
    const float hid1 = ema_csh[tid + 256] * DECAY + c1 * ONE_MINUS_DECAY;
    const float upd0 = hid0 / debias;
    const float upd1 = hid1 / debias;

    float v = upd0 + upd1;
#pragma unroll
    for (int m = 32; m >= 1; m >>= 1) v += __shfl_xor(v, m, 64);
    if ((tid & 63) == 0) s_red[tid >> 6] = v;
    __syncthreads();
    if (tid == 0) s_n = s_red[0] + s_red[1] + s_red[2] + s_red[3];
    __syncthreads();
    const float n = s_n;

    const int i  = b * 256 + tid;          // 0..32767
    const int kk = i & (K - 1);
    const int d  = i >> 9;
    const float updk   = (b & 1) ? upd1 : upd0;
    const float stable = (updk + 1e-5f) / (n + (float)K * 1e-5f) * n;
    const float hdw = ema_dwh[i] * DECAY + dw_t[kk * D + d] * ONE_MINUS_DECAY;
    out_hdw[i]  = hdw;
    out_nemb[i] = (hdw / debias) / stable;

    if (b == 0) {
        out_hcs[tid]       = hid0;
        out_hcs[tid + 256] = hid1;

        const float inv = 1.0f / (float)NROWS;
        float p0 = c0 * inv, p1 = c1 * inv;
        float ve = p0 * logf(p0 + 1e-10f) + p1 * logf(p1 + 1e-10f);
#pragma unroll
        for (int m = 32; m >= 1; m >>= 1) ve += __shfl_xor(ve, m, 64);
        __syncthreads();
        if ((tid & 63) == 0) s_red[tid >> 6] = ve;
        __syncthreads();
        if (tid < 32) {
            float lp = loss_parts[tid];
#pragma unroll
            for (int m = 16; m >= 1; m >>= 1) lp += __shfl_xor(lp, m, 64);
            if (tid == 0) {
                out_loss[0] = COMMIT * lp / (float)((size_t)NROWS * D);
                out_perp[0] = expf(-(s_red[0] + s_red[1] + s_red[2] + s_red[3]));
            }
        }
    }
}

// ---------------- launch ------------------------------------------------------
extern "C" void kernel_launch(void* const* d_in, const int* in_sizes, int n_in,
                              void* d_out, int out_size, void* d_ws, size_t ws_size,
                              hipStream_t stream)
{
    const float* x_in    = (const float*)d_in[0];   // [64,32,32,64]
    const float* emb     = (const float*)d_in[1];   // [64,512]
    const float* ema_csh = (const float*)d_in[2];   // [512]
    const float* ema_dwh = (const float*)d_in[3];   // [64,512]
    const int*   counter = (const int*)d_in[4];     // [1]

    float* ws  = (float*)d_ws;
    float* out = (float*)d_out;

    vq_prep<<<128, 256, 0, stream>>>(emb, ws);

    vq_main<<<NROWS / 32, 256, 0, stream>>>(
        x_in, ws + WS_ESQ, ws + WS_ET, ws + WS_EF,
        out + OUT_Q, out + OUT_IDX,
        (int*)(ws + WS_CNT), (int*)(ws + WS_PK), ws + WS_LPART);

    vq_perm<<<64, 512, 0, stream>>>(
        (const int*)(ws + WS_CNT), (const int*)(ws + WS_PK),
        (int*)(ws + WS_PERM));

    vq_dwsum<<<512, 256, 0, stream>>>(
        (const int*)(ws + WS_PERM), x_in, ws + WS_DWT);

    vq_final<<<128, 256, 0, stream>>>(
        (const int*)(ws + WS_CNT), ws + WS_LPART, ema_csh, counter,
        ema_dwh, ws + WS_DWT,
        out + OUT_LOSS, out + OUT_PERP, out + OUT_HCS,
        out + OUT_NEMB, out + OUT_HDW);
}

// Round 7
// 136.169 us; speedup vs baseline: 1.7252x; 1.1140x over previous
//
#include <hip/hip_runtime.h>
#include <math.h>

// Problem constants
#define D 64
#define K 512
#define NROWS 65536
#define DECAY 0.99f
#define ONE_MINUS_DECAY (1.0f - 0.99f)
#define COMMIT 0.25f

// ws layout (float offsets).  ATOMIC TARGETS ARE LINE-PADDED (stride 16
// dwords = 64B): 65536 rank-RMWs over 512 counters previously hit only 32
// cache lines (16 counters/line) -> ~2048 line-serialized RMWs per line
// (~38us).  Padding gives each counter its own line (128 RMWs/line).
#define WS_DWT    0              // [K][D] = 32768 floats, dw accumulator (zeroed)
#define WS_CNT    32768          // [K*16] ints, line-padded histogram (zeroed)
#define WS_LPART  40960          // [32*16] floats, line-padded loss parts (zeroed)
#define WS_ZERO4  10368          // float4 count zeroed by prep (41472 floats)
#define WS_ESQ    41472          // [K]   ||e_k||^2
#define WS_ET     41984          // [K][D] fp32 embeddings transposed (gather)
#define WS_EF     74752          // f16 MFMA B-fragments: 8192 x 16B = 32768 floats
#define WS_PK     107520         // [N] int packed (rank<<9 | k)
#define WS_PERM   41984          // [N] int packed (row<<9 | k) — ALIASES ET+EF
                                 // (both dead after vq_main; perm runs after)

// out layout (float offsets) — unchanged
#define OUT_Q     0
#define OUT_LOSS  4194304
#define OUT_PERP  4194305
#define OUT_IDX   4194306
#define OUT_NEMB  4259842
#define OUT_HCS   4292610
#define OUT_HDW   4293122

typedef _Float16 f16x8 __attribute__((ext_vector_type(8)));
typedef float    f32x16 __attribute__((ext_vector_type(16)));

// ---------------- prep: zero accum + e_t + ||e||^2 + f16 hi/lo B-fragments ---
// B-fragment layout for v_mfma_f32_32x32x16_f16:
//   lane l supplies col = tile*32 + (l&31), k = (l>>5)*8 + j (j=0..7)
// fragment block index i = ((t*4 + s)*2 + h)*64 + l  (s=kstep, h=0 hi / 1 lo)
__global__ void vq_prep(const float* __restrict__ emb,  // [D][K]
                        float* __restrict__ ws)
{
    int i = blockIdx.x * 256 + threadIdx.x;   // 0..32767 (128 blocks)
    if (i < WS_ZERO4) {                       // zero dw_t + padded cnt + lparts
        ((float4*)ws)[i] = make_float4(0.f, 0.f, 0.f, 0.f);
    }
    if (i < K * D) {                          // e_t[k][d] = emb[d][k]
        int k = i >> 6, d = i & 63;
        ws[WS_ET + i] = emb[d * K + k];
    }
    if (i < K) {                              // ||e_k||^2
        float s = 0.f;
        for (int d = 0; d < D; ++d) { float v = emb[d * K + i]; s += v * v; }
        ws[WS_ESQ + i] = s;
    }
    if (i < 8192) {                           // f16 hi/lo fragment buffer
        int l = i & 63, h = (i >> 6) & 1, s = (i >> 7) & 3, t = i >> 9;
        int col = t * 32 + (l & 31);
        int d0  = s * 16 + ((l >> 5) << 3);
        f16x8 frag;
#pragma unroll
        for (int j = 0; j < 8; ++j) {
            float v = emb[(d0 + j) * K + col];
            _Float16 hv = (_Float16)v;
            frag[j] = h ? (_Float16)(v - (float)hv) : hv;
        }
        ((f16x8*)(ws + WS_EF))[i] = frag;
    }
}

// ---------------- main: MFMA distances, K-split x4 across waves --------------
// Block = 4 waves = ONE 32-row MFMA tile; wave w handles code tiles 4w..4w+3.
// Identical to round-6 (zero-spill, ~92 VGPR) EXCEPT the two atomic targets
// are line-padded: cnt[bk<<4] and loss_parts[(bid&31)<<4].
// Loss identity: sum((q-x)^2) = sum_rows(||x||^2 + best_score).
// C/D layout: col = lane&31, row = (reg&3) + 8*(reg>>2) + 4*(lane>>5).
__global__ __launch_bounds__(256, 4)
void vq_main(const float* __restrict__ x,     // [N][D]
             const float* __restrict__ e_sq,  // [K]
             const float* __restrict__ e_t,   // [K][D] fp32
             const float* __restrict__ ef,    // f16 fragment buffer
             float* __restrict__ out_q,       // [N][D]
             float* __restrict__ out_idx,     // [N] (float)
             int*   __restrict__ cnt,         // [K*16] line-padded histogram
             int*   __restrict__ pk,          // [N] packed (rank<<9 | k)
             float* __restrict__ loss_parts)  // [32*16] line-padded
{
    __shared__ float sc_s[4][32];
    __shared__ int   id_s[4][32];
    __shared__ int   idx_f[32];

    const int tid  = threadIdx.x;
    const int w    = tid >> 6;
    const int l    = tid & 63;
    const int lr   = l & 31;       // A-row / B-col / C-col within tile
    const int hb   = l >> 5;       // k-group select
    const int row0 = blockIdx.x * 32;

    // ---- A fragments: lane supplies row (row0+lr), k = s*16 + hb*8 + j.
    f16x8 ah[4], al[4];
    float xsq = 0.f;
    {
        const float* xr = x + (size_t)(row0 + lr) * D + hb * 8;
#pragma unroll
        for (int s = 0; s < 4; ++s) {
            float4 f0 = *(const float4*)(xr + s * 16);
            float4 f1 = *(const float4*)(xr + s * 16 + 4);
            float f[8] = {f0.x, f0.y, f0.z, f0.w, f1.x, f1.y, f1.z, f1.w};
#pragma unroll
            for (int j = 0; j < 8; ++j) {
                xsq = fmaf(f[j], f[j], xsq);
                _Float16 hv = (_Float16)f[j];
                ah[s][j] = hv;
                al[s][j] = (_Float16)(f[j] - (float)hv);
            }
        }
    }

    float    best[16];
    unsigned pack = 0u;            // 2-bit best-tile index per acc reg
#pragma unroll
    for (int r = 0; r < 16; ++r) best[r] = 3.0e38f;

    const f16x8* __restrict__ efv = (const f16x8*)ef;

#pragma unroll 2
    for (int tt = 0; tt < 4; ++tt) {
        const int t = w * 4 + tt;           // global code tile
        f32x16 acc = {};
#pragma unroll
        for (int s = 0; s < 4; ++s) {
            f16x8 bh = efv[(t * 8 + s * 2 + 0) * 64 + l];
            f16x8 bl = efv[(t * 8 + s * 2 + 1) * 64 + l];
            acc = __builtin_amdgcn_mfma_f32_32x32x16_f16(al[s], bh, acc, 0, 0, 0);
            acc = __builtin_amdgcn_mfma_f32_32x32x16_f16(ah[s], bl, acc, 0, 0, 0);
            acc = __builtin_amdgcn_mfma_f32_32x32x16_f16(ah[s], bh, acc, 0, 0, 0);
        }

        const float eq = e_sq[t * 32 + lr];
#pragma unroll
        for (int r = 0; r < 16; ++r) {
            float sc = fmaf(-2.0f, acc[r], eq);
            bool better = sc < best[r];             // strict: earlier (smaller
            unsigned nb = (pack & ~(3u << (2 * r))) // k) tile wins ties
                        | ((unsigned)tt << (2 * r));
            best[r] = better ? sc : best[r];        // == v_min_f32
            pack    = better ? nb : pack;
        }
    }

    // ---- argmin reduce across the 32 lanes of each half (rows of this half)
#pragma unroll
    for (int r = 0; r < 16; ++r) {
        float b  = best[r];
        int   bk = (w * 4 + (int)((pack >> (2 * r)) & 3u)) * 32 + lr;
#pragma unroll
        for (int m = 16; m >= 1; m >>= 1) {
            float ob  = __shfl_xor(b, m, 64);
            int   obk = __shfl_xor(bk, m, 64);
            if (ob < b || (ob == b && obk < bk)) { b = ob; bk = obk; }
        }
        if (lr == 0) {
            int row = (r & 3) + 8 * (r >> 2) + 4 * hb;
            sc_s[w][row] = b;
            id_s[w][row] = bk;
        }
    }

    // ---- exact ||x||^2 block total (wave 0 covers all 32 rows x both halves)
    float xs_total = 0.f;
    if (w == 0) {
        float xs = xsq;
#pragma unroll
        for (int m = 32; m >= 1; m >>= 1) xs += __shfl_xor(xs, m, 64);
        xs_total = xs;
    }
    __syncthreads();

    // ---- combine across waves (wave order = ascending k: strict < keeps
    // smallest k on ties, matching argmax-first semantics) + outputs
    if (tid < 32) {
        float b = sc_s[0][tid]; int bk = id_s[0][tid];
#pragma unroll
        for (int w2 = 1; w2 < 4; ++w2) {
            float ob = sc_s[w2][tid];
            int  obk = id_s[w2][tid];
            if (ob < b) { b = ob; bk = obk; }
        }
        idx_f[tid] = bk;
        out_idx[row0 + tid] = (float)bk;
        int rank = atomicAdd(&cnt[bk << 4], 1);     // line-padded counter
        pk[row0 + tid] = (rank << 9) | bk;

        float lb = b;                      // sum of best scores over 32 rows
#pragma unroll
        for (int m = 16; m >= 1; m >>= 1) lb += __shfl_xor(lb, m, 64);
        if (tid == 0)
            atomicAdd(&loss_parts[(blockIdx.x & 31) << 4], lb + xs_total);
    }
    __syncthreads();

    // ---- gather + out_q: wave w writes rows 8w..8w+7, lane = d -------------
#pragma unroll
    for (int rr = 0; rr < 8; ++rr) {
        const int row = w * 8 + rr;
        const int kk  = idx_f[row];
        out_q[(size_t)(row0 + row) * D + l] = e_t[kk * D + l];
    }
}

// ---------------- perm build: per-block redundant scan + scatter -------------
// 64 blocks x 512.  Each block scans the 512-entry (padded) histogram in LDS
// (Hillis-Steele), then scatters its 1024 rows: perm[offs[k]+rank] = row|k.
__global__ __launch_bounds__(512)
void vq_perm(const int* __restrict__ cnt,   // [K*16] line-padded
             const int* __restrict__ pk,    // [N] (rank<<9 | k)
             int* __restrict__ perm)        // [N] (row<<9 | k), k-sorted
{
    __shared__ int s[K];

    const int t = threadIdx.x;            // 0..511
    const int c0 = cnt[t << 4];
    s[t] = c0;
    __syncthreads();
#pragma unroll
    for (int off = 1; off < K; off <<= 1) {
        int v = (t >= off) ? s[t - off] : 0;
        __syncthreads();
        s[t] += v;
        __syncthreads();
    }
    const int offs = s[t] - c0;           // exclusive prefix
    __syncthreads();
    s[t] = offs;
    __syncthreads();

#pragma unroll
    for (int it = 0; it < 2; ++it) {
        int row = blockIdx.x * 1024 + it * 512 + t;
        int v   = pk[row];
        int kk  = v & (K - 1);
        int rk  = v >> 9;
        perm[s[kk] + rk] = (row << 9) | kk;
    }
}

// ---------------- dw segmented reduce over k-sorted perm ---------------------
// 512 blocks x 256 = 2048 waves; wave w owns perm chunk [32w, 32w+32).
// lane = d.  k is wave-uniform per entry -> flush only at run boundaries.
__global__ __launch_bounds__(256, 2)
void vq_dwsum(const int* __restrict__ perm,  // [N] (row<<9 | k)
              const float* __restrict__ x,   // [N][D]
              float* __restrict__ dw_t)      // [K][D] accumulate
{
    const int w = (blockIdx.x * 256 + threadIdx.x) >> 6;  // 0..2047
    const int l = threadIdx.x & 63;

    int pv = 0;
    if (l < 32) pv = perm[w * 32 + l];

    float sum = 0.f;
    int kcur = -1;
#pragma unroll
    for (int e = 0; e < 32; ++e) {
        int pe  = __shfl(pv, e, 64);
        int kk  = pe & (K - 1);
        int row = pe >> 9;
        float xv = x[(size_t)row * D + l];
        if (kk != kcur) {                       // wave-uniform branch
            if (kcur >= 0) atomicAdd(&dw_t[kcur * D + l], sum);
            kcur = kk; sum = xv;
        } else {
            sum += xv;
        }
    }
    atomicAdd(&dw_t[kcur * D + l], sum);
}

// ---------------- finalize: scalars + hdw + new embeddings -------------------
// 128 blocks x 256.  Every block redundantly recomputes debias and the
// n-reduction from the (padded) histogram (L2-resident).
__global__ __launch_bounds__(256)
void vq_final(const int*   __restrict__ cnt,         // [K*16] line-padded
              const float* __restrict__ loss_parts,  // [32*16] line-padded
              const float* __restrict__ ema_csh,     // [K]
              const int*   __restrict__ counter,
              const float* __restrict__ ema_dwh,     // [D][K]
              const float* __restrict__ dw_t,        // [K][D]
              float* __restrict__ out_loss,
              float* __restrict__ out_perp,
              float* __restrict__ out_hcs,           // [K]
              float* __restrict__ out_nemb,          // [D][K]
              float* __restrict__ out_hdw)           // [D][K]
{
    __shared__ float s_red[4];
    __shared__ float s_n;

    const int tid = threadIdx.x;
    const int b   = blockIdx.x;

    const int   cntr   = counter[0] + 1;
    const float debias = 1.0f - powf(DECAY, (float)cntr);

    const float c0 = (float)cnt[tid << 4];
    const float c1 = (float)cnt[(tid + 256) << 4];
    const float hid0 = ema_csh[tid] * DECAY + c0 * ONE_MINUS_DECAY;
    const float hid1 = ema_csh[tid + 256] * DECAY + c1 * ONE_MINUS_DECAY;
    const float upd0 = hid0 / debias;
    const float upd1 = hid1 / debias;

    float v = upd0 + upd1;
#pragma unroll
    for (int m = 32; m >= 1; m >>= 1) v += __shfl_xor(v, m, 64);
    if ((tid & 63) == 0) s_red[tid >> 6] = v;
    __syncthreads();
    if (tid == 0) s_n = s_red[0] + s_red[1] + s_red[2] + s_red[3];
    __syncthreads();
    const float n = s_n;

    const int i  = b * 256 + tid;          // 0..32767
    const int kk = i & (K - 1);
    const int d  = i >> 9;
    const float updk   = (b & 1) ? upd1 : upd0;
    const float stable = (updk + 1e-5f) / (n + (float)K * 1e-5f) * n;
    const float hdw = ema_dwh[i] * DECAY + dw_t[kk * D + d] * ONE_MINUS_DECAY;
    out_hdw[i]  = hdw;
    out_nemb[i] = (hdw / debias) / stable;

    if (b == 0) {
        out_hcs[tid]       = hid0;
        out_hcs[tid + 256] = hid1;

        const float inv = 1.0f / (float)NROWS;
        float p0 = c0 * inv, p1 = c1 * inv;
        float ve = p0 * logf(p0 + 1e-10f) + p1 * logf(p1 + 1e-10f);
#pragma unroll
        for (int m = 32; m >= 1; m >>= 1) ve += __shfl_xor(ve, m, 64);
        __syncthreads();
        if ((tid & 63) == 0) s_red[tid >> 6] = ve;
        __syncthreads();
        if (tid < 32) {
            float lp = loss_parts[tid << 4];
#pragma unroll
            for (int m = 16; m >= 1; m >>= 1) lp += __shfl_xor(lp, m, 64);
            if (tid == 0) {
                out_loss[0] = COMMIT * lp / (float)((size_t)NROWS * D);
                out_perp[0] = expf(-(s_red[0] + s_red[1] + s_red[2] + s_red[3]));
            }
        }
    }
}

// ---------------- launch ------------------------------------------------------
extern "C" void kernel_launch(void* const* d_in, const int* in_sizes, int n_in,
                              void* d_out, int out_size, void* d_ws, size_t ws_size,
                              hipStream_t stream)
{
    const float* x_in    = (const float*)d_in[0];   // [64,32,32,64]
    const float* emb     = (const float*)d_in[1];   // [64,512]
    const float* ema_csh = (const float*)d_in[2];   // [512]
    const float* ema_dwh = (const float*)d_in[3];   // [64,512]
    const int*   counter = (const int*)d_in[4];     // [1]

    float* ws  = (float*)d_ws;
    float* out = (float*)d_out;

    vq_prep<<<128, 256, 0, stream>>>(emb, ws);

    vq_main<<<NROWS / 32, 256, 0, stream>>>(
        x_in, ws + WS_ESQ, ws + WS_ET, ws + WS_EF,
        out + OUT_Q, out + OUT_IDX,
        (int*)(ws + WS_CNT), (int*)(ws + WS_PK), ws + WS_LPART);

    vq_perm<<<64, 512, 0, stream>>>(
        (const int*)(ws + WS_CNT), (const int*)(ws + WS_PK),
        (int*)(ws + WS_PERM));

    vq_dwsum<<<512, 256, 0, stream>>>(
        (const int*)(ws + WS_PERM), x_in, ws + WS_DWT);

    vq_final<<<128, 256, 0, stream>>>(
        (const int*)(ws + WS_CNT), ws + WS_LPART, ema_csh, counter,
        ema_dwh, ws + WS_DWT,
        out + OUT_LOSS, out + OUT_PERP, out + OUT_HCS,
        out + OUT_NEMB, out + OUT_HDW);
}